// Round 7
// baseline (477.040 us; speedup 1.0000x reference)
//
#include <hip/hip_runtime.h>
#include <hip/hip_bf16.h>

// SpectralAttentionLayer: ChebConv(K=3) -> relu -> GATv2(heads=1)
// N=100000, E=1600000, D=32.  All float inputs f32 (device detector kept as
// insurance), output f32.
// Round-7: k_gat was VALU/issue-bound (92% VALUBusy). Softmax now uses a
// per-node upper bound K (shift-invariant, no online rescale), __expf,
// max-form lrelu; all gather loops are 16-edge branch-free double-issue;
// cheb+fsd fused (hc in LDS only) with fused per-dim |fsrc| max for K;
// sort payload packed to u32.

typedef unsigned short u16;

#define DD 32
#define NEG_SLOPE 0.2f
#define BLK 256
#define TILE 8192            // edges per pass-1 tile
#define CB_SHIFT 9           // coarse bucket = dst >> 9 (512 nodes)
#define CB_NODES 512
#define SRC_BITS 17          // N=100000 < 2^17

// weight block offsets inside wsW (floats)
#define OFF_CHEBW 0      // 3072
#define OFF_CHEBB 3072   // 32
#define OFF_SRCW  3104   // 1024
#define OFF_SRCB  4128   // 32
#define OFF_DSTW  4160   // 1024
#define OFF_DSTB  5184   // 32
#define OFF_ATTN  5216   // 32
#define OFF_LMAX  5248   // 1
#define W_TOTAL   5249

// flags indices (1 = f32 storage, 0 = bf16 storage)
#define F_U     0
#define F_CHEBW 1
#define F_CHEBB 2
#define F_SRCW  3
#define F_SRCB  4
#define F_DSTW  5
#define F_DSTB  6
#define F_ATTN  7
#define F_LMAX  8
#define N_FLAGS 9

__device__ __forceinline__ float bh2f(u16 h) {
    return __uint_as_float(((unsigned)h) << 16);
}
__device__ __forceinline__ float rdin(const void* p, long long i, int f32f) {
    return f32f ? ((const float*)p)[i] : bh2f(((const u16*)p)[i]);
}
__device__ __forceinline__ float4 rd4(const void* p, long long row, int q, int f32f) {
    if (f32f) return ((const float4*)p)[row * 8 + q];
    ushort4 h = ((const ushort4*)p)[row * 8 + q];
    return make_float4(bh2f(h.x), bh2f(h.y), bh2f(h.z), bh2f(h.w));
}
// leaky-relu(0.2): for x>=0 x >= 0.2x, for x<0 0.2x > x  ->  max form (2 insts)
__device__ __forceinline__ float lrelu(float x) { return fmaxf(x, NEG_SLOPE * x); }

__device__ __forceinline__ int plaus(u16 h) {
    if ((h & 0x7FFFu) == 0) return 1;
    unsigned e = (h >> 7) & 0xFF;
    return (e >= 0x60 && e <= 0x8F) ? 1 : 0;
}

// one block per array; 64 threads vote on even halfwords
__global__ void k_detect(const void* p0, const void* p1, const void* p2,
                         const void* p3, const void* p4, const void* p5,
                         const void* p6, const void* p7, const void* p8,
                         int n0, int n7, int* __restrict__ flags) {
    __shared__ int cEven, cEvenZ, cOddNZ;
    const void* ptrs[N_FLAGS] = {p0, p1, p2, p3, p4, p5, p6, p7, p8};
    const int   ns[N_FLAGS]   = {n0, 3072, 32, 1024, 32, 1024, 32, n7, 1};
    int a = blockIdx.x;
    if (a >= N_FLAGS) return;
    const u16* h = (const u16*)ptrs[a];
    int n = ns[a];
    if (threadIdx.x == 0) { cEven = 0; cEvenZ = 0; cOddNZ = 0; }
    __syncthreads();
    if (n == 1) {
        if (threadIdx.x == 0) {
            u16 v = h[0];
            flags[a] = ((v & 0x7FFFu) == 0 || !plaus(v)) ? 1 : 0;
        }
        return;
    }
    int nprobe = n >> 1;
    if (nprobe > 64) nprobe = 64;
    int t = threadIdx.x;
    if (t < nprobe) {
        u16 ev = h[2 * t];
        u16 od = h[2 * t + 1];
        if (plaus(ev)) atomicAdd(&cEven, 1);
        if ((ev & 0x7FFFu) == 0) atomicAdd(&cEvenZ, 1);
        if (plaus(od) && (od & 0x7FFFu) != 0) atomicAdd(&cOddNZ, 1);
    }
    __syncthreads();
    if (threadIdx.x == 0) {
        int bf = (cEven * 4 >= nprobe * 3);
        if (cEvenZ == nprobe && cOddNZ * 2 >= nprobe) bf = 0;
        flags[a] = bf ? 0 : 1;
    }
}

__global__ void k_cvtw(const void* chebW, const void* chebB, const void* srcW,
                       const void* srcB, const void* dstW, const void* dstB,
                       const void* attn, const void* lmax,
                       const int* __restrict__ flags, float* __restrict__ wsW) {
    int i = blockIdx.x * blockDim.x + threadIdx.x;
    if (i >= W_TOTAL) return;
    float v;
    if      (i < OFF_CHEBB) v = rdin(chebW, i - OFF_CHEBW, flags[F_CHEBW]);
    else if (i < OFF_SRCW)  v = rdin(chebB, i - OFF_CHEBB, flags[F_CHEBB]);
    else if (i < OFF_SRCB)  v = rdin(srcW,  i - OFF_SRCW,  flags[F_SRCW]);
    else if (i < OFF_DSTW)  v = rdin(srcB,  i - OFF_SRCB,  flags[F_SRCB]);
    else if (i < OFF_DSTB)  v = rdin(dstW,  i - OFF_DSTW,  flags[F_DSTW]);
    else if (i < OFF_ATTN)  v = rdin(dstB,  i - OFF_DSTB,  flags[F_DSTB]);
    else if (i < OFF_LMAX)  v = rdin(attn,  i - OFF_ATTN,  flags[F_ATTN]);
    else                    v = rdin(lmax,  0,             flags[F_LMAX]);
    wsW[i] = v;
}

// ---------------- two-level counting sort ----------------

__global__ __launch_bounds__(BLK) void k_h1(
        const int* __restrict__ dst, unsigned* __restrict__ hist1,
        int E, int T, int NB1) {
    __shared__ unsigned lh[256];
    int tile = blockIdx.x, t = threadIdx.x;
    lh[t] = 0;
    __syncthreads();
    int base = tile * TILE;
    for (int i = 0; i < TILE / BLK; i++) {
        int e = base + i * BLK + t;
        if (e < E) atomicAdd(&lh[dst[e] >> CB_SHIFT], 1u);
    }
    __syncthreads();
    for (int b = t; b < NB1; b += BLK) hist1[(size_t)b * T + tile] = lh[b];
}

__global__ __launch_bounds__(1024) void k_sc(
        unsigned* __restrict__ h, int M, unsigned* __restrict__ row_ptr,
        int N, int E) {
    __shared__ unsigned s[1024];
    int t = threadIdx.x;
    int C = (M + 1023) >> 10;
    int lo = t * C, hi = lo + C;
    if (hi > M) hi = M;
    unsigned sum = 0;
    for (int i = lo; i < hi; i++) sum += h[i];
    s[t] = sum;
    __syncthreads();
    for (int off = 1; off < 1024; off <<= 1) {
        unsigned a = (t >= off) ? s[t - off] : 0u;
        __syncthreads();
        s[t] += a;
        __syncthreads();
    }
    unsigned base = s[t] - sum;
    for (int i = lo; i < hi; i++) {
        unsigned v = h[i];
        h[i] = base;
        base += v;
    }
    if (t == 0) row_ptr[N] = (unsigned)E;
}

// pass-1 scatter: packed (local_dst<<17 | src) -> tmp grouped by coarse bucket
__global__ __launch_bounds__(BLK) void k_s1(
        const int* __restrict__ src, const int* __restrict__ dst,
        const unsigned* __restrict__ off1, unsigned* __restrict__ tmp,
        int E, int T, int NB1) {
    __shared__ unsigned cur[256];
    int tile = blockIdx.x, t = threadIdx.x;
    for (int b = t; b < NB1; b += BLK) cur[b] = off1[(size_t)b * T + tile];
    __syncthreads();
    int base = tile * TILE;
    for (int i = 0; i < TILE / BLK; i++) {
        int e = base + i * BLK + t;
        if (e < E) {
            int d = dst[e];
            unsigned pos = atomicAdd(&cur[d >> CB_SHIFT], 1u);
            tmp[pos] = ((unsigned)(d & (CB_NODES - 1)) << SRC_BITS) | (unsigned)src[e];
        }
    }
}

// pass-2: block per coarse bucket; fine LDS counting sort; emits row_ptr,
// dinv, srcs
__global__ __launch_bounds__(BLK) void k_p2(
        const unsigned* __restrict__ tmp, const unsigned* __restrict__ off1,
        unsigned* __restrict__ row_ptr, float* __restrict__ dinv,
        int* __restrict__ srcs, int N, int E, int T, int NB1) {
    __shared__ unsigned hist[CB_NODES], offs[CB_NODES], cur[CB_NODES], ssc[BLK];
    int b = blockIdx.x, t = threadIdx.x;
    int nodeBase = b << CB_SHIFT;
    unsigned lo = off1[(size_t)b * T];
    unsigned hi = (b + 1 < NB1) ? off1[(size_t)(b + 1) * T] : (unsigned)E;
    hist[t] = 0; hist[t + BLK] = 0;
    __syncthreads();
    for (unsigned e = lo + t; e < hi; e += BLK)
        atomicAdd(&hist[tmp[e] >> SRC_BITS], 1u);
    __syncthreads();
    unsigned a0 = hist[2 * t], a1 = hist[2 * t + 1];
    unsigned ps = a0 + a1;
    ssc[t] = ps;
    __syncthreads();
    for (int off = 1; off < BLK; off <<= 1) {
        unsigned a = (t >= off) ? ssc[t - off] : 0u;
        __syncthreads();
        ssc[t] += a;
        __syncthreads();
    }
    unsigned pbase = ssc[t] - ps;
    offs[2 * t] = pbase;
    offs[2 * t + 1] = pbase + a0;
    cur[2 * t] = pbase;
    cur[2 * t + 1] = pbase + a0;
    for (int k = 0; k < 2; k++) {
        int i = 2 * t + k;
        int node = nodeBase + i;
        if (node < N) {
            row_ptr[node] = lo + offs[i];
            unsigned c = hist[i];
            if (c < 1u) c = 1u;
            dinv[node] = rsqrtf((float)c);
        }
    }
    __syncthreads();
    for (unsigned e = lo + t; e < hi; e += BLK) {
        unsigned p = tmp[e];
        unsigned pos = lo + atomicAdd(&cur[p >> SRC_BITS], 1u);
        srcs[pos] = (int)(p & ((1u << SRC_BITS) - 1u));
    }
}

// ---------------- wave-per-node gather kernels ----------------
// 64-lane wave per dst node; q = lane&7 -> float4 dim group, g = lane>>3.
// 16 edges per iteration, branch-free (clamped index + zero weight) so both
// load groups issue back-to-back (16 lines in flight per wave).

__global__ __launch_bounds__(BLK) void k_unnl1(
        const void* __restrict__ u, const int* __restrict__ flags,
        const float* __restrict__ dinv, const unsigned* __restrict__ row_ptr,
        const int* __restrict__ srcs, const float* __restrict__ wsW,
        float* __restrict__ X1, int N) {
    int wave = (blockIdx.x * BLK + threadIdx.x) >> 6;
    if (wave >= N) return;
    int lane = threadIdx.x & 63, q = lane & 7, g = lane >> 3;
    int f = flags[F_U];
    int base = (int)row_ptr[wave], end = (int)row_ptr[wave + 1];
    float4 acc = make_float4(0.f, 0.f, 0.f, 0.f);
    for (int i = base; i < end; i += 16) {
        int e0 = i + g, e1 = i + 8 + g;
        int ec0 = min(e0, end - 1), ec1 = min(e1, end - 1);
        int s0 = srcs[ec0], s1 = srcs[ec1];
        float dv0 = dinv[s0], dv1 = dinv[s1];
        if (e0 >= end) dv0 = 0.f;
        if (e1 >= end) dv1 = 0.f;
        float4 x0 = rd4(u, s0, q, f);
        float4 x1 = rd4(u, s1, q, f);
        acc.x += x0.x * dv0 + x1.x * dv1;
        acc.y += x0.y * dv0 + x1.y * dv1;
        acc.z += x0.z * dv0 + x1.z * dv1;
        acc.w += x0.w * dv0 + x1.w * dv1;
    }
#pragma unroll
    for (int off = 8; off <= 32; off <<= 1) {
        acc.x += __shfl_xor(acc.x, off);
        acc.y += __shfl_xor(acc.y, off);
        acc.z += __shfl_xor(acc.z, off);
        acc.w += __shfl_xor(acc.w, off);
    }
    if (g == 0) {
        float rn = 2.0f / wsW[OFF_LMAX];
        float dn = dinv[wave];
        float4 x0 = rd4(u, wave, q, f);
        float4 r;
        r.x = -rn * (acc.x * dn) + x0.x * (rn - 1.f);
        r.y = -rn * (acc.y * dn) + x0.y * (rn - 1.f);
        r.z = -rn * (acc.z * dn) + x0.z * (rn - 1.f);
        r.w = -rn * (acc.w * dn) + x0.w * (rn - 1.f);
        ((float4*)X1)[(size_t)wave * 8 + q] = r;
    }
}

__global__ __launch_bounds__(BLK) void k_unnl2(
        const void* __restrict__ u, const int* __restrict__ flags,
        const float* __restrict__ X1, const float* __restrict__ dinv,
        const unsigned* __restrict__ row_ptr, const int* __restrict__ srcs,
        const float* __restrict__ wsW, float* __restrict__ X2, int N) {
    int wave = (blockIdx.x * BLK + threadIdx.x) >> 6;
    if (wave >= N) return;
    int lane = threadIdx.x & 63, q = lane & 7, g = lane >> 3;
    int base = (int)row_ptr[wave], end = (int)row_ptr[wave + 1];
    float4 acc = make_float4(0.f, 0.f, 0.f, 0.f);
    for (int i = base; i < end; i += 16) {
        int e0 = i + g, e1 = i + 8 + g;
        int ec0 = min(e0, end - 1), ec1 = min(e1, end - 1);
        int s0 = srcs[ec0], s1 = srcs[ec1];
        float dv0 = dinv[s0], dv1 = dinv[s1];
        if (e0 >= end) dv0 = 0.f;
        if (e1 >= end) dv1 = 0.f;
        float4 x0 = ((const float4*)X1)[(size_t)s0 * 8 + q];
        float4 x1 = ((const float4*)X1)[(size_t)s1 * 8 + q];
        acc.x += x0.x * dv0 + x1.x * dv1;
        acc.y += x0.y * dv0 + x1.y * dv1;
        acc.z += x0.z * dv0 + x1.z * dv1;
        acc.w += x0.w * dv0 + x1.w * dv1;
    }
#pragma unroll
    for (int off = 8; off <= 32; off <<= 1) {
        acc.x += __shfl_xor(acc.x, off);
        acc.y += __shfl_xor(acc.y, off);
        acc.z += __shfl_xor(acc.z, off);
        acc.w += __shfl_xor(acc.w, off);
    }
    if (g == 0) {
        float rn = 2.0f / wsW[OFF_LMAX];
        float dn = dinv[wave];
        float4 x0 = rd4(u, wave, q, flags[F_U]);
        float4 x1 = ((const float4*)X1)[(size_t)wave * 8 + q];
        float4 r;
        r.x = -2.f * rn * (acc.x * dn) + x1.x * (2.f * (rn - 1.f)) - x0.x;
        r.y = -2.f * rn * (acc.y * dn) + x1.y * (2.f * (rn - 1.f)) - x0.y;
        r.z = -2.f * rn * (acc.z * dn) + x1.z * (2.f * (rn - 1.f)) - x0.z;
        r.w = -2.f * rn * (acc.w * dn) + x1.w * (2.f * (rn - 1.f)) - x0.w;
        ((float4*)X2)[(size_t)wave * 8 + q] = r;
    }
}

// ---------------- fused cheb + src/dst projections ----------------
// hc lives only in LDS; also accumulates per-dim max|fsrc| for the GAT bound.
__global__ __launch_bounds__(BLK) void k_cfsd(
        const void* __restrict__ u, const int* __restrict__ flags,
        const float* __restrict__ X1, const float* __restrict__ X2,
        const float* __restrict__ wsW, float* __restrict__ fsrc,
        float* __restrict__ fdst, unsigned* __restrict__ Mabs, int ND) {
    __shared__ float sW[3072], sWs[1024], sWd[1024];
    __shared__ float sb[32], sbs[32], sbd[32];
    __shared__ float hcT[BLK];
    __shared__ unsigned mloc[32];
    int t = threadIdx.x;
    for (int i = t; i < 3072; i += BLK) sW[i] = wsW[OFF_CHEBW + i];
    for (int i = t; i < 1024; i += BLK) {
        sWs[i] = wsW[OFF_SRCW + i];
        sWd[i] = wsW[OFF_DSTW + i];
    }
    if (t < 32) {
        sb[t]  = wsW[OFF_CHEBB + t];
        sbs[t] = wsW[OFF_SRCB + t];
        sbd[t] = wsW[OFF_DSTB + t];
        mloc[t] = 0u;
    }
    __syncthreads();
    int idx = blockIdx.x * BLK + t;
    int valid = idx < ND;
    int j = t & 31;
    float hcv = 0.f;
    if (valid) {
        int f = flags[F_U];
        long long base = (long long)(idx >> 5) * 32;
        float acc = sb[j];
#pragma unroll
        for (int i = 0; i < 32; i++) acc = fmaf(rdin(u, base + i, f), sW[i * 32 + j], acc);
#pragma unroll
        for (int i = 0; i < 32; i++) acc = fmaf(X1[base + i], sW[(32 + i) * 32 + j], acc);
#pragma unroll
        for (int i = 0; i < 32; i++) acc = fmaf(X2[base + i], sW[(64 + i) * 32 + j], acc);
        hcv = fmaxf(acc, 0.f);
    }
    hcT[t] = hcv;
    __syncthreads();
    if (valid) {
        int lb = t & ~31;           // this node's row base in hcT
        float as = sbs[j], ad = sbd[j];
#pragma unroll
        for (int i = 0; i < 32; i++) {
            float hv = hcT[lb + i];
            as = fmaf(hv, sWs[i * 32 + j], as);
            ad = fmaf(hv, sWd[i * 32 + j], ad);
        }
        fsrc[idx] = as;
        fdst[idx] = ad;
        atomicMax(&mloc[j], __float_as_uint(fabsf(as)));  // nonneg: uint cmp == float cmp
    }
    __syncthreads();
    if (t < 32) atomicMax(&Mabs[t], mloc[t]);
}

// ---------------- fused GATv2, bound-shifted softmax, single pass ----------
__global__ __launch_bounds__(BLK) void k_gat(
        const float* __restrict__ fsrc, const float* __restrict__ fdst,
        const unsigned* __restrict__ row_ptr, const int* __restrict__ srcs,
        const float* __restrict__ wsW, const unsigned* __restrict__ Mabs,
        float* __restrict__ out, int N) {
    int wave = (blockIdx.x * BLK + threadIdx.x) >> 6;
    if (wave >= N) return;
    int lane = threadIdx.x & 63, q = lane & 7, g = lane >> 3;
    int base = (int)row_ptr[wave], end = (int)row_ptr[wave + 1];
    if (base == end) {
        if (g == 0)
            ((float4*)out)[(size_t)wave * 8 + q] = make_float4(0.f, 0.f, 0.f, 0.f);
        return;
    }
    float4 fd = ((const float4*)fdst)[(size_t)wave * 8 + q];
    float4 at = ((const float4*)(wsW + OFF_ATTN))[q];
    // K = sum_d (Mabs_d + |fd_d|) * |at_d| >= every logit of this node
    float4 mb = ((const float4*)Mabs)[q];   // bits of nonneg floats
    float kp = (mb.x + fabsf(fd.x)) * fabsf(at.x) +
               (mb.y + fabsf(fd.y)) * fabsf(at.y) +
               (mb.z + fabsf(fd.z)) * fabsf(at.z) +
               (mb.w + fabsf(fd.w)) * fabsf(at.w);
    kp += __shfl_xor(kp, 1);
    kp += __shfl_xor(kp, 2);
    kp += __shfl_xor(kp, 4);
    float K = kp;
    float4 acc = make_float4(0.f, 0.f, 0.f, 0.f);
    float den = 0.f;
    for (int i = base; i < end; i += 16) {
        int e0 = i + g, e1 = i + 8 + g;
        int ec0 = min(e0, end - 1), ec1 = min(e1, end - 1);
        int s0 = srcs[ec0], s1 = srcs[ec1];
        float4 fs0 = ((const float4*)fsrc)[(size_t)s0 * 8 + q];
        float4 fs1 = ((const float4*)fsrc)[(size_t)s1 * 8 + q];
        float v0 = lrelu(fs0.x + fd.x) * at.x + lrelu(fs0.y + fd.y) * at.y +
                   lrelu(fs0.z + fd.z) * at.z + lrelu(fs0.w + fd.w) * at.w;
        float v1 = lrelu(fs1.x + fd.x) * at.x + lrelu(fs1.y + fd.y) * at.y +
                   lrelu(fs1.z + fd.z) * at.z + lrelu(fs1.w + fd.w) * at.w;
        v0 += __shfl_xor(v0, 1);  v1 += __shfl_xor(v1, 1);
        v0 += __shfl_xor(v0, 2);  v1 += __shfl_xor(v1, 2);
        v0 += __shfl_xor(v0, 4);  v1 += __shfl_xor(v1, 4);
        float w0 = (e0 < end) ? __expf(v0 - K) : 0.f;
        float w1 = (e1 < end) ? __expf(v1 - K) : 0.f;
        acc.x += fs0.x * w0 + fs1.x * w1;
        acc.y += fs0.y * w0 + fs1.y * w1;
        acc.z += fs0.z * w0 + fs1.z * w1;
        acc.w += fs0.w * w0 + fs1.w * w1;
        den += w0 + w1;
    }
#pragma unroll
    for (int off = 8; off <= 32; off <<= 1) {
        acc.x += __shfl_xor(acc.x, off);
        acc.y += __shfl_xor(acc.y, off);
        acc.z += __shfl_xor(acc.z, off);
        acc.w += __shfl_xor(acc.w, off);
        den   += __shfl_xor(den, off);
    }
    if (g == 0) {
        float inv = 1.f / (den > 0.f ? den : 1.f);
        ((float4*)out)[(size_t)wave * 8 + q] =
            make_float4(acc.x * inv, acc.y * inv, acc.z * inv, acc.w * inv);
    }
}

extern "C" void kernel_launch(void* const* d_in, const int* in_sizes, int n_in,
                              void* d_out, int out_size, void* d_ws, size_t ws_size,
                              hipStream_t stream) {
    const void* u     = d_in[0];
    const void* lmax  = d_in[1];
    const int*  esrc  = (const int*)d_in[2];
    const int*  edst  = (const int*)d_in[3];
    const void* chebW = d_in[4];
    const void* chebB = d_in[5];
    const void* srcW  = d_in[6];
    const void* srcB  = d_in[7];
    const void* dstW  = d_in[8];
    const void* dstB  = d_in[9];
    const void* attn  = d_in[10];

    const int ND = in_sizes[0];   // N*32
    const int N  = ND / DD;
    const int E  = in_sizes[2];

    const int NB1 = (N + CB_NODES - 1) >> CB_SHIFT;     // 196
    const int T   = (E + TILE - 1) / TILE;              // 196
    const int M   = NB1 * T;

    // ws layout (~40 MB): X1[ND](->fsrc) | X2[ND](->fdst) | tmp[E u32]
    //  | srcs[E] | hist1[M] | row_ptr[N+1] | dinv[N] | wsW | flags | Mabs[32]
    float* ws   = (float*)d_ws;
    float* X1   = ws;
    float* X2   = ws + (size_t)ND;
    unsigned* tmp = (unsigned*)(ws + 2 * (size_t)ND);
    int*   srcs = (int*)(tmp + E);
    unsigned* hist1   = (unsigned*)(srcs + E);
    unsigned* row_ptr = hist1 + M;
    float*    dinv    = (float*)(row_ptr + (N + 1));
    float*    wsW     = (float*)(((uintptr_t)(dinv + N) + 15) & ~(uintptr_t)15);
    int*      flags   = (int*)(wsW + W_TOTAL);
    unsigned* Mabs    = (unsigned*)(((uintptr_t)(flags + N_FLAGS) + 15) & ~(uintptr_t)15);
    float*    out     = (float*)d_out;

    auto gb = [](long long n, int b) { return (unsigned)((n + b - 1) / b); };

    k_detect<<<N_FLAGS, 64, 0, stream>>>(u, chebW, chebB, srcW, srcB, dstW, dstB,
                                         attn, lmax, ND, DD, flags);
    k_cvtw<<<gb(W_TOTAL, BLK), BLK, 0, stream>>>(chebW, chebB, srcW, srcB, dstW, dstB,
                                                 attn, lmax, flags, wsW);
    hipMemsetAsync(Mabs, 0, 32 * sizeof(unsigned), stream);

    // two-level counting sort -> srcs (CSR payload), row_ptr, dinv
    k_h1<<<T, BLK, 0, stream>>>(edst, hist1, E, T, NB1);
    k_sc<<<1, 1024, 0, stream>>>(hist1, M, row_ptr, N, E);
    k_s1<<<T, BLK, 0, stream>>>(esrc, edst, hist1, tmp, E, T, NB1);
    k_p2<<<NB1, BLK, 0, stream>>>(tmp, hist1, row_ptr, dinv, srcs, N, E, T, NB1);

    // Chebyshev recursion via per-node gathers
    k_unnl1<<<gb((long long)N * 64, BLK), BLK, 0, stream>>>(u, flags, dinv, row_ptr,
                                                            srcs, wsW, X1, N);
    k_unnl2<<<gb((long long)N * 64, BLK), BLK, 0, stream>>>(u, flags, X1, dinv, row_ptr,
                                                            srcs, wsW, X2, N);

    // fused cheb + projections (fsrc->X1, fdst->X2; also Mabs for K bound)
    k_cfsd<<<gb(ND, BLK), BLK, 0, stream>>>(u, flags, X1, X2, wsW, X1, X2, Mabs, ND);

    // fused GATv2 (single pass, bound-shifted softmax)
    k_gat<<<gb((long long)N * 64, BLK), BLK, 0, stream>>>(X1, X2, row_ptr, srcs,
                                                          wsW, Mabs, out, N);
}

// Round 8
// 402.006 us; speedup vs baseline: 1.1866x; 1.1866x over previous
//
#include <hip/hip_runtime.h>
#include <hip/hip_bf16.h>

// SpectralAttentionLayer: ChebConv(K=3) -> relu -> GATv2(heads=1)
// N=100000, E=1600000, D=32.  All float inputs f32 (device detector kept as
// insurance), output f32.
// Round-8: k_cfsd rebuilt as grid-stride persistent kernel (round-7 version
// staged 20.5 KB of weights per 8 nodes -> 256 MB L2 traffic, 15% VALU,
// 160 us). Weights staged once per block; inputs loaded coalesced and
// broadcast with __shfl(width=32); no per-iteration barriers.

typedef unsigned short u16;

#define DD 32
#define NEG_SLOPE 0.2f
#define BLK 256
#define CFSD_BLOCKS 1024
#define TILE 8192            // edges per pass-1 tile
#define CB_SHIFT 9           // coarse bucket = dst >> 9 (512 nodes)
#define CB_NODES 512
#define SRC_BITS 17          // N=100000 < 2^17

// weight block offsets inside wsW (floats)
#define OFF_CHEBW 0      // 3072
#define OFF_CHEBB 3072   // 32
#define OFF_SRCW  3104   // 1024
#define OFF_SRCB  4128   // 32
#define OFF_DSTW  4160   // 1024
#define OFF_DSTB  5184   // 32
#define OFF_ATTN  5216   // 32
#define OFF_LMAX  5248   // 1
#define W_TOTAL   5249

// flags indices (1 = f32 storage, 0 = bf16 storage)
#define F_U     0
#define F_CHEBW 1
#define F_CHEBB 2
#define F_SRCW  3
#define F_SRCB  4
#define F_DSTW  5
#define F_DSTB  6
#define F_ATTN  7
#define F_LMAX  8
#define N_FLAGS 9

__device__ __forceinline__ float bh2f(u16 h) {
    return __uint_as_float(((unsigned)h) << 16);
}
__device__ __forceinline__ float rdin(const void* p, long long i, int f32f) {
    return f32f ? ((const float*)p)[i] : bh2f(((const u16*)p)[i]);
}
__device__ __forceinline__ float4 rd4(const void* p, long long row, int q, int f32f) {
    if (f32f) return ((const float4*)p)[row * 8 + q];
    ushort4 h = ((const ushort4*)p)[row * 8 + q];
    return make_float4(bh2f(h.x), bh2f(h.y), bh2f(h.z), bh2f(h.w));
}
__device__ __forceinline__ float lrelu(float x) { return fmaxf(x, NEG_SLOPE * x); }

__device__ __forceinline__ int plaus(u16 h) {
    if ((h & 0x7FFFu) == 0) return 1;
    unsigned e = (h >> 7) & 0xFF;
    return (e >= 0x60 && e <= 0x8F) ? 1 : 0;
}

// one block per array; 64 threads vote on even halfwords
__global__ void k_detect(const void* p0, const void* p1, const void* p2,
                         const void* p3, const void* p4, const void* p5,
                         const void* p6, const void* p7, const void* p8,
                         int n0, int n7, int* __restrict__ flags) {
    __shared__ int cEven, cEvenZ, cOddNZ;
    const void* ptrs[N_FLAGS] = {p0, p1, p2, p3, p4, p5, p6, p7, p8};
    const int   ns[N_FLAGS]   = {n0, 3072, 32, 1024, 32, 1024, 32, n7, 1};
    int a = blockIdx.x;
    if (a >= N_FLAGS) return;
    const u16* h = (const u16*)ptrs[a];
    int n = ns[a];
    if (threadIdx.x == 0) { cEven = 0; cEvenZ = 0; cOddNZ = 0; }
    __syncthreads();
    if (n == 1) {
        if (threadIdx.x == 0) {
            u16 v = h[0];
            flags[a] = ((v & 0x7FFFu) == 0 || !plaus(v)) ? 1 : 0;
        }
        return;
    }
    int nprobe = n >> 1;
    if (nprobe > 64) nprobe = 64;
    int t = threadIdx.x;
    if (t < nprobe) {
        u16 ev = h[2 * t];
        u16 od = h[2 * t + 1];
        if (plaus(ev)) atomicAdd(&cEven, 1);
        if ((ev & 0x7FFFu) == 0) atomicAdd(&cEvenZ, 1);
        if (plaus(od) && (od & 0x7FFFu) != 0) atomicAdd(&cOddNZ, 1);
    }
    __syncthreads();
    if (threadIdx.x == 0) {
        int bf = (cEven * 4 >= nprobe * 3);
        if (cEvenZ == nprobe && cOddNZ * 2 >= nprobe) bf = 0;
        flags[a] = bf ? 0 : 1;
    }
}

__global__ void k_cvtw(const void* chebW, const void* chebB, const void* srcW,
                       const void* srcB, const void* dstW, const void* dstB,
                       const void* attn, const void* lmax,
                       const int* __restrict__ flags, float* __restrict__ wsW) {
    int i = blockIdx.x * blockDim.x + threadIdx.x;
    if (i >= W_TOTAL) return;
    float v;
    if      (i < OFF_CHEBB) v = rdin(chebW, i - OFF_CHEBW, flags[F_CHEBW]);
    else if (i < OFF_SRCW)  v = rdin(chebB, i - OFF_CHEBB, flags[F_CHEBB]);
    else if (i < OFF_SRCB)  v = rdin(srcW,  i - OFF_SRCW,  flags[F_SRCW]);
    else if (i < OFF_DSTW)  v = rdin(srcB,  i - OFF_SRCB,  flags[F_SRCB]);
    else if (i < OFF_DSTB)  v = rdin(dstW,  i - OFF_DSTW,  flags[F_DSTW]);
    else if (i < OFF_ATTN)  v = rdin(dstB,  i - OFF_DSTB,  flags[F_DSTB]);
    else if (i < OFF_LMAX)  v = rdin(attn,  i - OFF_ATTN,  flags[F_ATTN]);
    else                    v = rdin(lmax,  0,             flags[F_LMAX]);
    wsW[i] = v;
}

// ---------------- two-level counting sort ----------------

__global__ __launch_bounds__(BLK) void k_h1(
        const int* __restrict__ dst, unsigned* __restrict__ hist1,
        int E, int T, int NB1) {
    __shared__ unsigned lh[256];
    int tile = blockIdx.x, t = threadIdx.x;
    lh[t] = 0;
    __syncthreads();
    int base = tile * TILE;
    for (int i = 0; i < TILE / BLK; i++) {
        int e = base + i * BLK + t;
        if (e < E) atomicAdd(&lh[dst[e] >> CB_SHIFT], 1u);
    }
    __syncthreads();
    for (int b = t; b < NB1; b += BLK) hist1[(size_t)b * T + tile] = lh[b];
}

__global__ __launch_bounds__(1024) void k_sc(
        unsigned* __restrict__ h, int M, unsigned* __restrict__ row_ptr,
        int N, int E) {
    __shared__ unsigned s[1024];
    int t = threadIdx.x;
    int C = (M + 1023) >> 10;
    int lo = t * C, hi = lo + C;
    if (hi > M) hi = M;
    unsigned sum = 0;
    for (int i = lo; i < hi; i++) sum += h[i];
    s[t] = sum;
    __syncthreads();
    for (int off = 1; off < 1024; off <<= 1) {
        unsigned a = (t >= off) ? s[t - off] : 0u;
        __syncthreads();
        s[t] += a;
        __syncthreads();
    }
    unsigned base = s[t] - sum;
    for (int i = lo; i < hi; i++) {
        unsigned v = h[i];
        h[i] = base;
        base += v;
    }
    if (t == 0) row_ptr[N] = (unsigned)E;
}

// pass-1 scatter: packed (local_dst<<17 | src) -> tmp grouped by coarse bucket
__global__ __launch_bounds__(BLK) void k_s1(
        const int* __restrict__ src, const int* __restrict__ dst,
        const unsigned* __restrict__ off1, unsigned* __restrict__ tmp,
        int E, int T, int NB1) {
    __shared__ unsigned cur[256];
    int tile = blockIdx.x, t = threadIdx.x;
    for (int b = t; b < NB1; b += BLK) cur[b] = off1[(size_t)b * T + tile];
    __syncthreads();
    int base = tile * TILE;
    for (int i = 0; i < TILE / BLK; i++) {
        int e = base + i * BLK + t;
        if (e < E) {
            int d = dst[e];
            unsigned pos = atomicAdd(&cur[d >> CB_SHIFT], 1u);
            tmp[pos] = ((unsigned)(d & (CB_NODES - 1)) << SRC_BITS) | (unsigned)src[e];
        }
    }
}

// pass-2: block per coarse bucket; fine LDS counting sort; emits row_ptr,
// dinv, srcs
__global__ __launch_bounds__(BLK) void k_p2(
        const unsigned* __restrict__ tmp, const unsigned* __restrict__ off1,
        unsigned* __restrict__ row_ptr, float* __restrict__ dinv,
        int* __restrict__ srcs, int N, int E, int T, int NB1) {
    __shared__ unsigned hist[CB_NODES], offs[CB_NODES], cur[CB_NODES], ssc[BLK];
    int b = blockIdx.x, t = threadIdx.x;
    int nodeBase = b << CB_SHIFT;
    unsigned lo = off1[(size_t)b * T];
    unsigned hi = (b + 1 < NB1) ? off1[(size_t)(b + 1) * T] : (unsigned)E;
    hist[t] = 0; hist[t + BLK] = 0;
    __syncthreads();
    for (unsigned e = lo + t; e < hi; e += BLK)
        atomicAdd(&hist[tmp[e] >> SRC_BITS], 1u);
    __syncthreads();
    unsigned a0 = hist[2 * t], a1 = hist[2 * t + 1];
    unsigned ps = a0 + a1;
    ssc[t] = ps;
    __syncthreads();
    for (int off = 1; off < BLK; off <<= 1) {
        unsigned a = (t >= off) ? ssc[t - off] : 0u;
        __syncthreads();
        ssc[t] += a;
        __syncthreads();
    }
    unsigned pbase = ssc[t] - ps;
    offs[2 * t] = pbase;
    offs[2 * t + 1] = pbase + a0;
    cur[2 * t] = pbase;
    cur[2 * t + 1] = pbase + a0;
    for (int k = 0; k < 2; k++) {
        int i = 2 * t + k;
        int node = nodeBase + i;
        if (node < N) {
            row_ptr[node] = lo + offs[i];
            unsigned c = hist[i];
            if (c < 1u) c = 1u;
            dinv[node] = rsqrtf((float)c);
        }
    }
    __syncthreads();
    for (unsigned e = lo + t; e < hi; e += BLK) {
        unsigned p = tmp[e];
        unsigned pos = lo + atomicAdd(&cur[p >> SRC_BITS], 1u);
        srcs[pos] = (int)(p & ((1u << SRC_BITS) - 1u));
    }
}

// ---------------- wave-per-node gather kernels ----------------

__global__ __launch_bounds__(BLK) void k_unnl1(
        const void* __restrict__ u, const int* __restrict__ flags,
        const float* __restrict__ dinv, const unsigned* __restrict__ row_ptr,
        const int* __restrict__ srcs, const float* __restrict__ wsW,
        float* __restrict__ X1, int N) {
    int wave = (blockIdx.x * BLK + threadIdx.x) >> 6;
    if (wave >= N) return;
    int lane = threadIdx.x & 63, q = lane & 7, g = lane >> 3;
    int f = flags[F_U];
    int base = (int)row_ptr[wave], end = (int)row_ptr[wave + 1];
    float4 acc = make_float4(0.f, 0.f, 0.f, 0.f);
    for (int i = base; i < end; i += 16) {
        int e0 = i + g, e1 = i + 8 + g;
        int ec0 = min(e0, end - 1), ec1 = min(e1, end - 1);
        int s0 = srcs[ec0], s1 = srcs[ec1];
        float dv0 = dinv[s0], dv1 = dinv[s1];
        if (e0 >= end) dv0 = 0.f;
        if (e1 >= end) dv1 = 0.f;
        float4 x0 = rd4(u, s0, q, f);
        float4 x1 = rd4(u, s1, q, f);
        acc.x += x0.x * dv0 + x1.x * dv1;
        acc.y += x0.y * dv0 + x1.y * dv1;
        acc.z += x0.z * dv0 + x1.z * dv1;
        acc.w += x0.w * dv0 + x1.w * dv1;
    }
#pragma unroll
    for (int off = 8; off <= 32; off <<= 1) {
        acc.x += __shfl_xor(acc.x, off);
        acc.y += __shfl_xor(acc.y, off);
        acc.z += __shfl_xor(acc.z, off);
        acc.w += __shfl_xor(acc.w, off);
    }
    if (g == 0) {
        float rn = 2.0f / wsW[OFF_LMAX];
        float dn = dinv[wave];
        float4 x0 = rd4(u, wave, q, f);
        float4 r;
        r.x = -rn * (acc.x * dn) + x0.x * (rn - 1.f);
        r.y = -rn * (acc.y * dn) + x0.y * (rn - 1.f);
        r.z = -rn * (acc.z * dn) + x0.z * (rn - 1.f);
        r.w = -rn * (acc.w * dn) + x0.w * (rn - 1.f);
        ((float4*)X1)[(size_t)wave * 8 + q] = r;
    }
}

__global__ __launch_bounds__(BLK) void k_unnl2(
        const void* __restrict__ u, const int* __restrict__ flags,
        const float* __restrict__ X1, const float* __restrict__ dinv,
        const unsigned* __restrict__ row_ptr, const int* __restrict__ srcs,
        const float* __restrict__ wsW, float* __restrict__ X2, int N) {
    int wave = (blockIdx.x * BLK + threadIdx.x) >> 6;
    if (wave >= N) return;
    int lane = threadIdx.x & 63, q = lane & 7, g = lane >> 3;
    int base = (int)row_ptr[wave], end = (int)row_ptr[wave + 1];
    float4 acc = make_float4(0.f, 0.f, 0.f, 0.f);
    for (int i = base; i < end; i += 16) {
        int e0 = i + g, e1 = i + 8 + g;
        int ec0 = min(e0, end - 1), ec1 = min(e1, end - 1);
        int s0 = srcs[ec0], s1 = srcs[ec1];
        float dv0 = dinv[s0], dv1 = dinv[s1];
        if (e0 >= end) dv0 = 0.f;
        if (e1 >= end) dv1 = 0.f;
        float4 x0 = ((const float4*)X1)[(size_t)s0 * 8 + q];
        float4 x1 = ((const float4*)X1)[(size_t)s1 * 8 + q];
        acc.x += x0.x * dv0 + x1.x * dv1;
        acc.y += x0.y * dv0 + x1.y * dv1;
        acc.z += x0.z * dv0 + x1.z * dv1;
        acc.w += x0.w * dv0 + x1.w * dv1;
    }
#pragma unroll
    for (int off = 8; off <= 32; off <<= 1) {
        acc.x += __shfl_xor(acc.x, off);
        acc.y += __shfl_xor(acc.y, off);
        acc.z += __shfl_xor(acc.z, off);
        acc.w += __shfl_xor(acc.w, off);
    }
    if (g == 0) {
        float rn = 2.0f / wsW[OFF_LMAX];
        float dn = dinv[wave];
        float4 x0 = rd4(u, wave, q, flags[F_U]);
        float4 x1 = ((const float4*)X1)[(size_t)wave * 8 + q];
        float4 r;
        r.x = -2.f * rn * (acc.x * dn) + x1.x * (2.f * (rn - 1.f)) - x0.x;
        r.y = -2.f * rn * (acc.y * dn) + x1.y * (2.f * (rn - 1.f)) - x0.y;
        r.z = -2.f * rn * (acc.z * dn) + x1.z * (2.f * (rn - 1.f)) - x0.z;
        r.w = -2.f * rn * (acc.w * dn) + x1.w * (2.f * (rn - 1.f)) - x0.w;
        ((float4*)X2)[(size_t)wave * 8 + q] = r;
    }
}

// ---------------- fused cheb + projections, grid-stride persistent ----------
// weights staged in LDS ONCE per block; node features loaded coalesced
// (lane j reads element j) and broadcast via __shfl(width=32); hc broadcast
// the same way; no per-iteration barriers.  fsrc aliases X1, fdst aliases X2:
// safe because each 32-lane group reads only its own row before writing it.
__global__ __launch_bounds__(BLK) void k_cfsd(
        const void* __restrict__ u, const int* __restrict__ flags,
        const float* __restrict__ X1, const float* __restrict__ X2,
        const float* __restrict__ wsW, float* __restrict__ fsrc,
        float* __restrict__ fdst, unsigned* __restrict__ Mabs, int ND) {
    __shared__ float sW[3072], sWs[1024], sWd[1024];
    __shared__ float sb[32], sbs[32], sbd[32];
    __shared__ unsigned mloc[32];
    int t = threadIdx.x;
    for (int i = t; i < 3072; i += BLK) sW[i] = wsW[OFF_CHEBW + i];
    for (int i = t; i < 1024; i += BLK) {
        sWs[i] = wsW[OFF_SRCW + i];
        sWd[i] = wsW[OFF_DSTW + i];
    }
    if (t < 32) {
        sb[t]  = wsW[OFF_CHEBB + t];
        sbs[t] = wsW[OFF_SRCB + t];
        sbd[t] = wsW[OFF_DSTB + t];
        mloc[t] = 0u;
    }
    __syncthreads();
    int f = flags[F_U];
    int j = t & 31;
    float mabs = 0.f;
    long long stride = (long long)gridDim.x * BLK;
    for (long long idx = (long long)blockIdx.x * BLK + t; idx < ND; idx += stride) {
        long long base = idx - j;                 // row start (idx = node*32 + j)
        float x0 = rdin(u, base + j, f);          // coalesced
        float x1 = X1[base + j];
        float x2 = X2[base + j];
        float acc = sb[j];
#pragma unroll
        for (int i = 0; i < 32; i++)
            acc = fmaf(__shfl(x0, i, 32), sW[i * 32 + j], acc);
#pragma unroll
        for (int i = 0; i < 32; i++)
            acc = fmaf(__shfl(x1, i, 32), sW[(32 + i) * 32 + j], acc);
#pragma unroll
        for (int i = 0; i < 32; i++)
            acc = fmaf(__shfl(x2, i, 32), sW[(64 + i) * 32 + j], acc);
        float hc = fmaxf(acc, 0.f);
        float as = sbs[j], ad = sbd[j];
#pragma unroll
        for (int i = 0; i < 32; i++) {
            float hv = __shfl(hc, i, 32);
            as = fmaf(hv, sWs[i * 32 + j], as);
            ad = fmaf(hv, sWd[i * 32 + j], ad);
        }
        fsrc[idx] = as;                           // coalesced (overwrites X1 row)
        fdst[idx] = ad;                           // coalesced (overwrites X2 row)
        mabs = fmaxf(mabs, fabsf(as));
    }
    atomicMax(&mloc[j], __float_as_uint(mabs));   // nonneg: uint cmp == float cmp
    __syncthreads();
    if (t < 32) atomicMax(&Mabs[t], mloc[t]);
}

// ---------------- fused GATv2, bound-shifted softmax, single pass ----------
__global__ __launch_bounds__(BLK) void k_gat(
        const float* __restrict__ fsrc, const float* __restrict__ fdst,
        const unsigned* __restrict__ row_ptr, const int* __restrict__ srcs,
        const float* __restrict__ wsW, const unsigned* __restrict__ Mabs,
        float* __restrict__ out, int N) {
    int wave = (blockIdx.x * BLK + threadIdx.x) >> 6;
    if (wave >= N) return;
    int lane = threadIdx.x & 63, q = lane & 7, g = lane >> 3;
    int base = (int)row_ptr[wave], end = (int)row_ptr[wave + 1];
    if (base == end) {
        if (g == 0)
            ((float4*)out)[(size_t)wave * 8 + q] = make_float4(0.f, 0.f, 0.f, 0.f);
        return;
    }
    float4 fd = ((const float4*)fdst)[(size_t)wave * 8 + q];
    float4 at = ((const float4*)(wsW + OFF_ATTN))[q];
    // K = sum_d (Mabs_d + |fd_d|) * |at_d| >= every logit of this node
    float4 mb = ((const float4*)Mabs)[q];   // bits of nonneg floats
    float kp = (mb.x + fabsf(fd.x)) * fabsf(at.x) +
               (mb.y + fabsf(fd.y)) * fabsf(at.y) +
               (mb.z + fabsf(fd.z)) * fabsf(at.z) +
               (mb.w + fabsf(fd.w)) * fabsf(at.w);
    kp += __shfl_xor(kp, 1);
    kp += __shfl_xor(kp, 2);
    kp += __shfl_xor(kp, 4);
    float K = kp;
    float4 acc = make_float4(0.f, 0.f, 0.f, 0.f);
    float den = 0.f;
    for (int i = base; i < end; i += 16) {
        int e0 = i + g, e1 = i + 8 + g;
        int ec0 = min(e0, end - 1), ec1 = min(e1, end - 1);
        int s0 = srcs[ec0], s1 = srcs[ec1];
        float4 fs0 = ((const float4*)fsrc)[(size_t)s0 * 8 + q];
        float4 fs1 = ((const float4*)fsrc)[(size_t)s1 * 8 + q];
        float v0 = lrelu(fs0.x + fd.x) * at.x + lrelu(fs0.y + fd.y) * at.y +
                   lrelu(fs0.z + fd.z) * at.z + lrelu(fs0.w + fd.w) * at.w;
        float v1 = lrelu(fs1.x + fd.x) * at.x + lrelu(fs1.y + fd.y) * at.y +
                   lrelu(fs1.z + fd.z) * at.z + lrelu(fs1.w + fd.w) * at.w;
        v0 += __shfl_xor(v0, 1);  v1 += __shfl_xor(v1, 1);
        v0 += __shfl_xor(v0, 2);  v1 += __shfl_xor(v1, 2);
        v0 += __shfl_xor(v0, 4);  v1 += __shfl_xor(v1, 4);
        float w0 = (e0 < end) ? __expf(v0 - K) : 0.f;
        float w1 = (e1 < end) ? __expf(v1 - K) : 0.f;
        acc.x += fs0.x * w0 + fs1.x * w1;
        acc.y += fs0.y * w0 + fs1.y * w1;
        acc.z += fs0.z * w0 + fs1.z * w1;
        acc.w += fs0.w * w0 + fs1.w * w1;
        den += w0 + w1;
    }
#pragma unroll
    for (int off = 8; off <= 32; off <<= 1) {
        acc.x += __shfl_xor(acc.x, off);
        acc.y += __shfl_xor(acc.y, off);
        acc.z += __shfl_xor(acc.z, off);
        acc.w += __shfl_xor(acc.w, off);
        den   += __shfl_xor(den, off);
    }
    if (g == 0) {
        float inv = 1.f / (den > 0.f ? den : 1.f);
        ((float4*)out)[(size_t)wave * 8 + q] =
            make_float4(acc.x * inv, acc.y * inv, acc.z * inv, acc.w * inv);
    }
}

extern "C" void kernel_launch(void* const* d_in, const int* in_sizes, int n_in,
                              void* d_out, int out_size, void* d_ws, size_t ws_size,
                              hipStream_t stream) {
    const void* u     = d_in[0];
    const void* lmax  = d_in[1];
    const int*  esrc  = (const int*)d_in[2];
    const int*  edst  = (const int*)d_in[3];
    const void* chebW = d_in[4];
    const void* chebB = d_in[5];
    const void* srcW  = d_in[6];
    const void* srcB  = d_in[7];
    const void* dstW  = d_in[8];
    const void* dstB  = d_in[9];
    const void* attn  = d_in[10];

    const int ND = in_sizes[0];   // N*32
    const int N  = ND / DD;
    const int E  = in_sizes[2];

    const int NB1 = (N + CB_NODES - 1) >> CB_SHIFT;     // 196
    const int T   = (E + TILE - 1) / TILE;              // 196
    const int M   = NB1 * T;

    // ws layout (~40 MB): X1[ND](->fsrc) | X2[ND](->fdst) | tmp[E u32]
    //  | srcs[E] | hist1[M] | row_ptr[N+1] | dinv[N] | wsW | flags | Mabs[32]
    float* ws   = (float*)d_ws;
    float* X1   = ws;
    float* X2   = ws + (size_t)ND;
    unsigned* tmp = (unsigned*)(ws + 2 * (size_t)ND);
    int*   srcs = (int*)(tmp + E);
    unsigned* hist1   = (unsigned*)(srcs + E);
    unsigned* row_ptr = hist1 + M;
    float*    dinv    = (float*)(row_ptr + (N + 1));
    float*    wsW     = (float*)(((uintptr_t)(dinv + N) + 15) & ~(uintptr_t)15);
    int*      flags   = (int*)(wsW + W_TOTAL);
    unsigned* Mabs    = (unsigned*)(((uintptr_t)(flags + N_FLAGS) + 15) & ~(uintptr_t)15);
    float*    out     = (float*)d_out;

    auto gb = [](long long n, int b) { return (unsigned)((n + b - 1) / b); };

    k_detect<<<N_FLAGS, 64, 0, stream>>>(u, chebW, chebB, srcW, srcB, dstW, dstB,
                                         attn, lmax, ND, DD, flags);
    k_cvtw<<<gb(W_TOTAL, BLK), BLK, 0, stream>>>(chebW, chebB, srcW, srcB, dstW, dstB,
                                                 attn, lmax, flags, wsW);
    hipMemsetAsync(Mabs, 0, 32 * sizeof(unsigned), stream);

    // two-level counting sort -> srcs (CSR payload), row_ptr, dinv
    k_h1<<<T, BLK, 0, stream>>>(edst, hist1, E, T, NB1);
    k_sc<<<1, 1024, 0, stream>>>(hist1, M, row_ptr, N, E);
    k_s1<<<T, BLK, 0, stream>>>(esrc, edst, hist1, tmp, E, T, NB1);
    k_p2<<<NB1, BLK, 0, stream>>>(tmp, hist1, row_ptr, dinv, srcs, N, E, T, NB1);

    // Chebyshev recursion via per-node gathers
    k_unnl1<<<gb((long long)N * 64, BLK), BLK, 0, stream>>>(u, flags, dinv, row_ptr,
                                                            srcs, wsW, X1, N);
    k_unnl2<<<gb((long long)N * 64, BLK), BLK, 0, stream>>>(u, flags, X1, dinv, row_ptr,
                                                            srcs, wsW, X2, N);

    // fused cheb + projections (fsrc->X1, fdst->X2; also Mabs for K bound)
    k_cfsd<<<CFSD_BLOCKS, BLK, 0, stream>>>(u, flags, X1, X2, wsW, X1, X2, Mabs, ND);

    // fused GATv2 (single pass, bound-shifted softmax)
    k_gat<<<gb((long long)N * 64, BLK), BLK, 0, stream>>>(X1, X2, row_ptr, srcs,
                                                          wsW, Mabs, out, N);
}